// Round 21
// baseline (8010.419 us; speedup 1.0000x reference)
//
#include <hip/hip_runtime.h>
#include <hip/hip_bf16.h>
#include <stdint.h>

// LSTM B=64 S=1024 D=1024 H=1024, gates f,i,o,g all sigmoid.
// R21 = R20 (fused producers+consumers, U AGPR-pinned, 5.27ms) with the consumer
// h-load path swapped to R15's proven scheme: plain coalesced b128 loads + ONE
// acquire fence per step (after chunk-0 flags) + compiler barriers per wait.
// Rationale: atomic 8B loads = 2x fabric requests + no L2 sharing; R15's fence
// penalty (U L2-restream eviction) is gone now that U lives in AGPRs.

typedef __attribute__((ext_vector_type(8))) short short8;
typedef __attribute__((ext_vector_type(4))) float floatx4;
typedef __attribute__((ext_vector_type(2))) float floatx2;

__device__ __forceinline__ unsigned short f2bf(float x){
  union { float f; unsigned int u; } v; v.f = x;
  unsigned int r = v.u + 0x7fffu + ((v.u >> 16) & 1u);
  return (unsigned short)(r >> 16);
}
__device__ __forceinline__ float bf2f(unsigned short b){
  union { unsigned int u; float f; } v; v.u = ((unsigned int)b) << 16; return v.f;
}
__device__ __forceinline__ float fsigmoid(float x){ return 1.0f / (1.0f + __expf(-x)); }
__device__ __forceinline__ float ftanh(float x){ return 1.0f - 2.0f / (1.0f + __expf(2.0f * x)); }

// ---- transpose [g][d][h] fp32 -> [g][h][d] bf16 (per-gate 1024x1024) ----
__global__ void k_transpose_bf16(const float* __restrict__ src, unsigned short* __restrict__ dst){
  __shared__ float tile[64][65];
  const int g  = blockIdx.z;
  const int d0 = blockIdx.x * 64;
  const int h0 = blockIdx.y * 64;
  const int t  = threadIdx.x;
  const float* s    = src + ((size_t)g << 20);
  unsigned short* o = dst + ((size_t)g << 20);
  #pragma unroll
  for (int i = 0; i < 16; i++){
    int e = i * 256 + t;
    int r = e >> 6, c = e & 63;
    tile[r][c] = s[(size_t)(d0 + r) * 1024 + (h0 + c)];
  }
  __syncthreads();
  #pragma unroll
  for (int i = 0; i < 16; i++){
    int e = i * 256 + t;
    int a = e >> 6, bb = e & 63;
    o[(size_t)(h0 + a) * 1024 + (d0 + bb)] = f2bf(tile[bb][a]);
  }
}

// ---- convert input chunk (B,S,D) fp32 -> Abuf[(sl*64+b)][d] bf16 ----
__global__ void k_convert_x(const float* __restrict__ inp, unsigned short* __restrict__ abuf, int s0){
  int idx = blockIdx.x * 256 + threadIdx.x;
  int e = idx * 4;
  int r = e >> 10, d = e & 1023;
  int b = r & 63, sl = r >> 6;
  floatx4 v = *(const floatx4*)(inp + ((size_t)(b * 1024 + (s0 + sl)) * 1024 + d));
  unsigned long long pk = (unsigned long long)f2bf(v[0])
                        | ((unsigned long long)f2bf(v[1]) << 16)
                        | ((unsigned long long)f2bf(v[2]) << 32)
                        | ((unsigned long long)f2bf(v[3]) << 48);
  *(unsigned long long*)(abuf + (size_t)r * 1024 + d) = pk;
}

// ---- fused producer/consumer kernel ----
__global__ void __launch_bounds__(256, 1) k_fused(
    const unsigned short* __restrict__ Abuf, // [SC*64][1024] bf16
    const unsigned short* __restrict__ Wt,   // [4096][1024] bf16
    const float* __restrict__ bW,
    const float* __restrict__ bU,
    unsigned short* __restrict__ xp,         // [SC*64][4096] bf16
    const unsigned short* __restrict__ Ut,   // [4096][1024] bf16
    unsigned short* hbs,                     // [2][4][32768B]
    float* cstate,
    float* __restrict__ out,
    float* __restrict__ hlast,
    float* __restrict__ clast,
    int* flags,                              // [4][32]
    int* mcnt,                               // [SC/2] m-tile counters (zeroed)
    int s_base, int SC)
{
  union Smem {
    struct { unsigned short As[2][128][64]; unsigned short Bs[2][128][64]; } g;
    float glds[4][16][33];
  };
  __shared__ Smem sm;

  const int t = threadIdx.x;

  if (blockIdx.x < 128){
    // ================= producer: xproj GEMM =================
    const int pwg = blockIdx.x;
    const int w = t >> 6;
    const int lane = t & 63;
    const int ntiles = SC * 16;

    for (int tile = pwg; tile < ntiles; tile += 128){
      const int mt = tile >> 5, nt = tile & 31;
      const int m0 = mt * 128, n0 = nt * 128;

      floatx4 acc[4][4];
      #pragma unroll
      for (int i = 0; i < 4; i++)
        #pragma unroll
        for (int jj = 0; jj < 4; jj++)
          acc[i][jj] = (floatx4){0.f, 0.f, 0.f, 0.f};

      auto stage = [&](int bufi, int kt){
        #pragma unroll
        for (int i = 0; i < 4; i++){
          int chunk = i * 256 + t;
          int r = chunk >> 3, jx = chunk & 7;
          int js = jx ^ (r & 7);
          __builtin_amdgcn_global_load_lds(
            (const __attribute__((address_space(1))) unsigned int*)(Abuf + (size_t)(m0 + r) * 1024 + kt * 64 + js * 8),
            (__attribute__((address_space(3))) unsigned int*)(&sm.g.As[bufi][0][0] + (i * 256 + w * 64) * 8), 16, 0, 0);
        }
        #pragma unroll
        for (int i = 0; i < 4; i++){
          int chunk = i * 256 + t;
          int r = chunk >> 3, jx = chunk & 7;
          int js = jx ^ (r & 7);
          __builtin_amdgcn_global_load_lds(
            (const __attribute__((address_space(1))) unsigned int*)(Wt + (size_t)(n0 + r) * 1024 + kt * 64 + js * 8),
            (__attribute__((address_space(3))) unsigned int*)(&sm.g.Bs[bufi][0][0] + (i * 256 + w * 64) * 8), 16, 0, 0);
        }
      };

      auto compute = [&](int bufi){
        const int mi0 = (w >> 1) * 64;
        const int ni0 = (w & 1) * 64;
        #pragma unroll
        for (int kc = 0; kc < 2; kc++){
          short8 af[4], bfr[4];
          #pragma unroll
          for (int mi = 0; mi < 4; mi++){
            int row = mi0 + mi * 16 + (lane & 15);
            int jx = kc * 4 + (lane >> 4);
            af[mi] = *(const short8*)&sm.g.As[bufi][row][(jx ^ (row & 7)) * 8];
          }
          #pragma unroll
          for (int ni = 0; ni < 4; ni++){
            int row = ni0 + ni * 16 + (lane & 15);
            int jx = kc * 4 + (lane >> 4);
            bfr[ni] = *(const short8*)&sm.g.Bs[bufi][row][(jx ^ (row & 7)) * 8];
          }
          #pragma unroll
          for (int mi = 0; mi < 4; mi++)
            #pragma unroll
            for (int ni = 0; ni < 4; ni++)
              acc[mi][ni] = __builtin_amdgcn_mfma_f32_16x16x32_bf16(af[mi], bfr[ni], acc[mi][ni], 0, 0, 0);
        }
      };

      stage(0, 0);
      int buf = 0;
      for (int kt = 0; kt < 16; kt++){
        __syncthreads();
        if (kt < 15) stage(buf ^ 1, kt + 1);
        compute(buf);
        buf ^= 1;
      }

      {
        const int mi0 = (w >> 1) * 64;
        const int ni0 = (w & 1) * 64;
        #pragma unroll
        for (int ni = 0; ni < 4; ni++){
          int col = n0 + ni0 + ni * 16 + (lane & 15);
          float bias = bW[col] + bU[col];
          #pragma unroll
          for (int mi = 0; mi < 4; mi++){
            int mrow = m0 + mi0 + mi * 16 + (lane >> 4) * 4;
            #pragma unroll
            for (int r = 0; r < 4; r++)
              xp[(size_t)(mrow + r) * 4096 + col] = f2bf(acc[mi][ni][r] + bias);
          }
        }
      }

      asm volatile("s_waitcnt vmcnt(0)" ::: "memory");
      __syncthreads();
      if (t == 0){
        __builtin_amdgcn_fence(__ATOMIC_RELEASE, "agent");
        __hip_atomic_fetch_add(&mcnt[mt], 1, __ATOMIC_RELAXED, __HIP_MEMORY_SCOPE_AGENT);
      }
      __syncthreads();
    }
    return;
  }

  // ================= consumer: recurrence =================
  const int w = t >> 6;            // wave = gate
  const int lane = t & 63;
  const int wgid = blockIdx.x - 128;
  const int g  = wgid & 3;
  const int j  = wgid >> 2;
  const int B0 = g * 16;
  const int gc0 = j * 32;

  short8 bfrag0[32], bfrag1[32];
  {
    const unsigned short* bp0 = Ut + (size_t)(w * 1024 + gc0 + (lane & 15)) * 1024 + (lane >> 4) * 8;
    const unsigned short* bp1 = bp0 + (size_t)16 * 1024;
    #pragma unroll
    for (int kc = 0; kc < 32; kc++){
      bfrag0[kc] = *(const short8*)(bp0 + kc * 32);
      bfrag1[kc] = *(const short8*)(bp1 + kc * 32);
    }
  }

  const int b   = t >> 4;
  const int cc2 = (t & 15) * 2;
  floatx2 cst;
  if (s_base == 0) cst = (floatx2){0.f, 0.f};
  else             cst = *(const floatx2*)&cstate[(size_t)(B0 + b) * 1024 + gc0 + cc2];

  int bail = 20000000;
  const int fb = g * 32;

  for (int sl = 0; sl < SC; sl++){
    const int s = s_base + sl;
    const int p = s & 1;

    // gate on xproj m-tile (every other step)
    if (!(sl & 1)){
      const int mt = sl >> 1;
      while (true){
        int v = __hip_atomic_load(&mcnt[mt], __ATOMIC_RELAXED, __HIP_MEMORY_SCOPE_AGENT);
        if (__all(v >= 32)) break;
        __builtin_amdgcn_s_sleep(2);
        if (--bail < 0) break;
      }
      asm volatile("" ::: "memory");
    }

    const char* gsrc = (const char*)hbs + ((size_t)p * 4 + g) * 32768;
    floatx4 acc0 = (floatx4){0.f,0.f,0.f,0.f};
    floatx4 acc1 = (floatx4){0.f,0.f,0.f,0.f};

    // per-chunk wait: lanes 0-7 poll the 8 producer flags of chunk c
    auto wait_chunk = [&](int c){
      if (s == 0) return;
      while (true){
        bool ok = true;
        if (lane < 8){
          int v = __hip_atomic_load(&flags[fb + c * 8 + lane], __ATOMIC_RELAXED, __HIP_MEMORY_SCOPE_AGENT);
          ok = (v >= s);
        }
        if (__all(ok)) break;
        __builtin_amdgcn_s_sleep(1);
        if (--bail < 0) break;
      }
      asm volatile("" ::: "memory");   // stop plain-load hoisting above the confirm
    };

    wait_chunk(0);
    __builtin_amdgcn_fence(__ATOMIC_ACQUIRE, "agent");  // invalidate L1/L2 once per step
                                                        // (U is AGPR-resident: cheap now)
    // xp prefetch after the fence (fence drains vmcnt); hides under chunk loads
    unsigned int xu[4];
    {
      const unsigned short* xr = xp + ((size_t)(sl * 64 + B0 + b)) * 4096 + gc0 + cc2;
      #pragma unroll
      for (int gg = 0; gg < 4; gg++) xu[gg] = *(const unsigned int*)(xr + gg * 1024);
    }

    short8 hA[8], hB[8];
    auto issue8 = [&](short8 (&h)[8], int ch){
      #pragma unroll
      for (int i = 0; i < 8; i++)
        h[i] = *(const short8*)(gsrc + (ch * 8 + i) * 1024 + lane * 16);
    };
    auto crunch8 = [&](short8 (&h)[8], int ch){
      #pragma unroll
      for (int i = 0; i < 8; i++){
        asm volatile("s_nop 1\n\tv_mfma_f32_16x16x32_bf16 %0, %1, %2, %0"
                     : "+v"(acc0) : "v"(h[i]), "a"(bfrag0[ch * 8 + i]));
        asm volatile("v_mfma_f32_16x16x32_bf16 %0, %1, %2, %0"
                     : "+v"(acc1) : "v"(h[i]), "a"(bfrag1[ch * 8 + i]));
      }
    };

    issue8(hA, 0);
    wait_chunk(1);
    issue8(hB, 1);
    crunch8(hA, 0);
    wait_chunk(2);
    issue8(hA, 2);
    crunch8(hB, 1);
    wait_chunk(3);
    issue8(hB, 3);
    crunch8(hA, 2);
    crunch8(hB, 3);
    asm volatile("s_nop 7\n\ts_nop 7\n\ts_nop 7" ::: "memory");

    {
      const int r0 = (lane >> 4) * 4;
      const int cl = lane & 15;
      #pragma unroll
      for (int r = 0; r < 4; r++){
        sm.glds[w][r0 + r][cl]      = acc0[r];
        sm.glds[w][r0 + r][16 + cl] = acc1[r];
      }
    }
    __syncthreads();                                    // B3

    float hout[2];
    #pragma unroll
    for (int d = 0; d < 2; d++){
      float fv = fsigmoid(sm.glds[0][b][cc2 + d] + bf2f((unsigned short)(xu[0] >> (16 * d))));
      float iv = fsigmoid(sm.glds[1][b][cc2 + d] + bf2f((unsigned short)(xu[1] >> (16 * d))));
      float ov = fsigmoid(sm.glds[2][b][cc2 + d] + bf2f((unsigned short)(xu[2] >> (16 * d))));
      float gv = fsigmoid(sm.glds[3][b][cc2 + d] + bf2f((unsigned short)(xu[3] >> (16 * d))));  // sigmoid
      float cv = fv * cst[d] + iv * gv;
      cst[d] = cv;
      hout[d] = ov * ftanh(cv);
    }

    {
      unsigned int hv = (unsigned int)f2bf(hout[0]) | ((unsigned int)f2bf(hout[1]) << 16);
      unsigned int* dst = (unsigned int*)((char*)hbs + ((size_t)(p ^ 1) * 4 + g) * 32768 + j * 1024
                + (((cc2 >> 3) * 16 + b) << 4) + ((cc2 & 7) << 1));
      __hip_atomic_store(dst, hv, __ATOMIC_RELAXED, __HIP_MEMORY_SCOPE_AGENT);
    }

    if (s == 1023){
      *(floatx2*)&hlast[(size_t)(B0 + b) * 1024 + gc0 + cc2] = (floatx2){hout[0], hout[1]};
      *(floatx2*)&clast[(size_t)(B0 + b) * 1024 + gc0 + cc2] = cst;
    }

    asm volatile("s_waitcnt vmcnt(0)" ::: "memory");
    __syncthreads();                                    // B4
    if (t == 0)
      __hip_atomic_store(&flags[fb + j], s + 1, __ATOMIC_RELAXED, __HIP_MEMORY_SCOPE_AGENT);

    *(floatx2*)&out[((size_t)(B0 + b) * 1024 + s) * 1024 + gc0 + cc2] = (floatx2){hout[0], hout[1]};
  }

  *(floatx2*)&cstate[(size_t)(B0 + b) * 1024 + gc0 + cc2] = cst;
}

extern "C" void kernel_launch(void* const* d_in, const int* in_sizes, int n_in,
                              void* d_out, int out_size, void* d_ws, size_t ws_size,
                              hipStream_t stream)
{
  (void)in_sizes; (void)n_in; (void)out_size;
  const float* input_emb = (const float*)d_in[0];
  const float* W   = (const float*)d_in[1];
  const float* bWp = (const float*)d_in[2];
  const float* U   = (const float*)d_in[3];
  const float* bUp = (const float*)d_in[4];
  float* out   = (float*)d_out;
  float* hlast = out + (size_t)64 * 1024 * 1024;
  float* clast = hlast + 64 * 1024;

  char* base = (char*)d_ws;
  unsigned short* Wt  = (unsigned short*)base;  base += 8388608;   // [4096][1024] bf16
  unsigned short* Ut  = (unsigned short*)base;  base += 8388608;   // [4096][1024] bf16
  unsigned short* hbs = (unsigned short*)base;  base += 262144;    // [2][4][32KB] group h
  float* cstate       = (float*)base;           base += 262144;    // [64][1024] f32
  int* flags          = (int*)base;             base += 8192;      // [4][32] ints (+pad)
  int* mcnt           = (int*)base;             base += 4096;      // [SC/2] m-tile counters
  size_t fixed = (size_t)(base - (char*)d_ws);
  size_t avail = ws_size > fixed ? ws_size - fixed : 0;
  int SC = 1024;
  while (SC > 8 && (size_t)SC * 655360ull > avail) SC >>= 1;
  unsigned short* Abuf = (unsigned short*)base; base += (size_t)SC * 131072;  // [SC*64][1024] bf16
  unsigned short* xpb  = (unsigned short*)base;                               // [SC*64][4096] bf16

  hipMemsetAsync(flags, 0, 8192, stream);
  hipMemsetAsync(hbs, 0, 262144, stream);       // h0 = 0 (both parities)

  k_transpose_bf16<<<dim3(16, 16, 4), 256, 0, stream>>>(W, Wt);
  k_transpose_bf16<<<dim3(16, 16, 4), 256, 0, stream>>>(U, Ut);

  int nch = 1024 / SC;
  for (int cc = 0; cc < nch; cc++){
    int s0 = cc * SC;
    hipMemsetAsync(mcnt, 0, 4096, stream);
    k_convert_x<<<SC * 64, 256, 0, stream>>>(input_emb, Abuf, s0);
    k_fused<<<256, 256, 0, stream>>>(Abuf, Wt, bWp, bUp, xpb, Ut, hbs, cstate,
                                     out, hlast, clast, flags, mcnt, s0, SC);
  }
}

// Round 22
// 5286.918 us; speedup vs baseline: 1.5151x; 1.5151x over previous
//
#include <hip/hip_runtime.h>
#include <hip/hip_bf16.h>
#include <stdint.h>

// LSTM B=64 S=1024 D=1024 H=1024, gates f,i,o,g all sigmoid.
// R22 = R20 verbatim (best verified: 5.27ms total). Fused kernel: WGs 0-127 =
// persistent xproj GEMM producers, WGs 128-255 = recurrence with AGPR-pinned U,
// agent-scope atomic h publish/consume (L2-neutral), per-chunk flag overlap.
// R21's fence-based consume regressed 52% (L2 invalidation starves co-resident
// producers) -> atomic consume is confirmed optimal for this structure.

typedef __attribute__((ext_vector_type(8))) short short8;
typedef __attribute__((ext_vector_type(4))) float floatx4;
typedef __attribute__((ext_vector_type(2))) float floatx2;

__device__ __forceinline__ unsigned short f2bf(float x){
  union { float f; unsigned int u; } v; v.f = x;
  unsigned int r = v.u + 0x7fffu + ((v.u >> 16) & 1u);
  return (unsigned short)(r >> 16);
}
__device__ __forceinline__ float bf2f(unsigned short b){
  union { unsigned int u; float f; } v; v.u = ((unsigned int)b) << 16; return v.f;
}
__device__ __forceinline__ float fsigmoid(float x){ return 1.0f / (1.0f + __expf(-x)); }
__device__ __forceinline__ float ftanh(float x){ return 1.0f - 2.0f / (1.0f + __expf(2.0f * x)); }

// ---- transpose [g][d][h] fp32 -> [g][h][d] bf16 (per-gate 1024x1024) ----
__global__ void k_transpose_bf16(const float* __restrict__ src, unsigned short* __restrict__ dst){
  __shared__ float tile[64][65];
  const int g  = blockIdx.z;
  const int d0 = blockIdx.x * 64;
  const int h0 = blockIdx.y * 64;
  const int t  = threadIdx.x;
  const float* s    = src + ((size_t)g << 20);
  unsigned short* o = dst + ((size_t)g << 20);
  #pragma unroll
  for (int i = 0; i < 16; i++){
    int e = i * 256 + t;
    int r = e >> 6, c = e & 63;
    tile[r][c] = s[(size_t)(d0 + r) * 1024 + (h0 + c)];
  }
  __syncthreads();
  #pragma unroll
  for (int i = 0; i < 16; i++){
    int e = i * 256 + t;
    int a = e >> 6, bb = e & 63;
    o[(size_t)(h0 + a) * 1024 + (d0 + bb)] = f2bf(tile[bb][a]);
  }
}

// ---- convert input chunk (B,S,D) fp32 -> Abuf[(sl*64+b)][d] bf16 ----
__global__ void k_convert_x(const float* __restrict__ inp, unsigned short* __restrict__ abuf, int s0){
  int idx = blockIdx.x * 256 + threadIdx.x;
  int e = idx * 4;
  int r = e >> 10, d = e & 1023;
  int b = r & 63, sl = r >> 6;
  floatx4 v = *(const floatx4*)(inp + ((size_t)(b * 1024 + (s0 + sl)) * 1024 + d));
  unsigned long long pk = (unsigned long long)f2bf(v[0])
                        | ((unsigned long long)f2bf(v[1]) << 16)
                        | ((unsigned long long)f2bf(v[2]) << 32)
                        | ((unsigned long long)f2bf(v[3]) << 48);
  *(unsigned long long*)(abuf + (size_t)r * 1024 + d) = pk;
}

// ---- fused producer/consumer kernel ----
// WGs 0-127: persistent xproj GEMM producers. WGs 128-255: recurrence (R19 body).
// xp layout [SC*64][4096]; m-tile mt covers rows [mt*128, mt*128+128) = steps 2mt,2mt+1.
// mcnt[mt] counts completed n-tiles (32 = ready). hbs/flags as in R12/R19.
__global__ void __launch_bounds__(256, 1) k_fused(
    const unsigned short* __restrict__ Abuf, // [SC*64][1024] bf16
    const unsigned short* __restrict__ Wt,   // [4096][1024] bf16
    const float* __restrict__ bW,
    const float* __restrict__ bU,
    unsigned short* __restrict__ xp,         // [SC*64][4096] bf16
    const unsigned short* __restrict__ Ut,   // [4096][1024] bf16
    unsigned short* hbs,                     // [2][4][32768B]
    float* cstate,
    float* __restrict__ out,
    float* __restrict__ hlast,
    float* __restrict__ clast,
    int* flags,                              // [4][32]
    int* mcnt,                               // [SC/2] m-tile counters (zeroed)
    int s_base, int SC)
{
  union Smem {
    struct { unsigned short As[2][128][64]; unsigned short Bs[2][128][64]; } g;
    float glds[4][16][33];
  };
  __shared__ Smem sm;

  const int t = threadIdx.x;

  if (blockIdx.x < 128){
    // ================= producer: xproj GEMM =================
    const int pwg = blockIdx.x;
    const int w = t >> 6;
    const int lane = t & 63;
    const int ntiles = SC * 16;              // (SC*64/128) m-tiles * 32 n-tiles

    for (int tile = pwg; tile < ntiles; tile += 128){
      const int mt = tile >> 5, nt = tile & 31;
      const int m0 = mt * 128, n0 = nt * 128;

      floatx4 acc[4][4];
      #pragma unroll
      for (int i = 0; i < 4; i++)
        #pragma unroll
        for (int jj = 0; jj < 4; jj++)
          acc[i][jj] = (floatx4){0.f, 0.f, 0.f, 0.f};

      auto stage = [&](int bufi, int kt){
        #pragma unroll
        for (int i = 0; i < 4; i++){
          int chunk = i * 256 + t;
          int r = chunk >> 3, jx = chunk & 7;
          int js = jx ^ (r & 7);
          __builtin_amdgcn_global_load_lds(
            (const __attribute__((address_space(1))) unsigned int*)(Abuf + (size_t)(m0 + r) * 1024 + kt * 64 + js * 8),
            (__attribute__((address_space(3))) unsigned int*)(&sm.g.As[bufi][0][0] + (i * 256 + w * 64) * 8), 16, 0, 0);
        }
        #pragma unroll
        for (int i = 0; i < 4; i++){
          int chunk = i * 256 + t;
          int r = chunk >> 3, jx = chunk & 7;
          int js = jx ^ (r & 7);
          __builtin_amdgcn_global_load_lds(
            (const __attribute__((address_space(1))) unsigned int*)(Wt + (size_t)(n0 + r) * 1024 + kt * 64 + js * 8),
            (__attribute__((address_space(3))) unsigned int*)(&sm.g.Bs[bufi][0][0] + (i * 256 + w * 64) * 8), 16, 0, 0);
        }
      };

      auto compute = [&](int bufi){
        const int mi0 = (w >> 1) * 64;
        const int ni0 = (w & 1) * 64;
        #pragma unroll
        for (int kc = 0; kc < 2; kc++){
          short8 af[4], bfr[4];
          #pragma unroll
          for (int mi = 0; mi < 4; mi++){
            int row = mi0 + mi * 16 + (lane & 15);
            int jx = kc * 4 + (lane >> 4);
            af[mi] = *(const short8*)&sm.g.As[bufi][row][(jx ^ (row & 7)) * 8];
          }
          #pragma unroll
          for (int ni = 0; ni < 4; ni++){
            int row = ni0 + ni * 16 + (lane & 15);
            int jx = kc * 4 + (lane >> 4);
            bfr[ni] = *(const short8*)&sm.g.Bs[bufi][row][(jx ^ (row & 7)) * 8];
          }
          #pragma unroll
          for (int mi = 0; mi < 4; mi++)
            #pragma unroll
            for (int ni = 0; ni < 4; ni++)
              acc[mi][ni] = __builtin_amdgcn_mfma_f32_16x16x32_bf16(af[mi], bfr[ni], acc[mi][ni], 0, 0, 0);
        }
      };

      stage(0, 0);
      int buf = 0;
      for (int kt = 0; kt < 16; kt++){
        __syncthreads();
        if (kt < 15) stage(buf ^ 1, kt + 1);
        compute(buf);
        buf ^= 1;
      }

      {
        const int mi0 = (w >> 1) * 64;
        const int ni0 = (w & 1) * 64;
        #pragma unroll
        for (int ni = 0; ni < 4; ni++){
          int col = n0 + ni0 + ni * 16 + (lane & 15);
          float bias = bW[col] + bU[col];
          #pragma unroll
          for (int mi = 0; mi < 4; mi++){
            int mrow = m0 + mi0 + mi * 16 + (lane >> 4) * 4;
            #pragma unroll
            for (int r = 0; r < 4; r++)
              xp[(size_t)(mrow + r) * 4096 + col] = f2bf(acc[mi][ni][r] + bias);
          }
        }
      }

      // release this tile: all waves drain, then t0 publishes to L3 + counts
      asm volatile("s_waitcnt vmcnt(0)" ::: "memory");
      __syncthreads();
      if (t == 0){
        __builtin_amdgcn_fence(__ATOMIC_RELEASE, "agent");
        __hip_atomic_fetch_add(&mcnt[mt], 1, __ATOMIC_RELAXED, __HIP_MEMORY_SCOPE_AGENT);
      }
      __syncthreads();
    }
    return;
  }

  // ================= consumer: recurrence (R19 body) =================
  const int w = t >> 6;            // wave = gate
  const int lane = t & 63;
  const int wgid = blockIdx.x - 128;
  const int g  = wgid & 3;         // batch group: batches 16g..16g+15
  const int j  = wgid >> 2;        // col-slice: h-cols [j*32, j*32+32)
  const int B0 = g * 16;
  const int gc0 = j * 32;

  short8 bfrag0[32], bfrag1[32];
  {
    const unsigned short* bp0 = Ut + (size_t)(w * 1024 + gc0 + (lane & 15)) * 1024 + (lane >> 4) * 8;
    const unsigned short* bp1 = bp0 + (size_t)16 * 1024;
    #pragma unroll
    for (int kc = 0; kc < 32; kc++){
      bfrag0[kc] = *(const short8*)(bp0 + kc * 32);
      bfrag1[kc] = *(const short8*)(bp1 + kc * 32);
    }
  }

  const int b   = t >> 4;
  const int cc2 = (t & 15) * 2;
  floatx2 cst;
  if (s_base == 0) cst = (floatx2){0.f, 0.f};
  else             cst = *(const floatx2*)&cstate[(size_t)(B0 + b) * 1024 + gc0 + cc2];

  int bail = 20000000;
  const int fb = g * 32;

  for (int sl = 0; sl < SC; sl++){
    const int s = s_base + sl;
    const int p = s & 1;

    // gate on xproj m-tile (every other step); uniform-address poll per wave
    if (!(sl & 1)){
      const int mt = sl >> 1;
      while (true){
        int v = __hip_atomic_load(&mcnt[mt], __ATOMIC_RELAXED, __HIP_MEMORY_SCOPE_AGENT);
        if (__all(v >= 32)) break;
        __builtin_amdgcn_s_sleep(2);
        if (--bail < 0) break;
      }
      asm volatile("" ::: "memory");
    }

    // xp prefetch (gated): 2 cols per gate as one 4B load
    unsigned int xu[4];
    {
      const unsigned short* xr = xp + ((size_t)(sl * 64 + B0 + b)) * 4096 + gc0 + cc2;
      #pragma unroll
      for (int gg = 0; gg < 4; gg++) xu[gg] = *(const unsigned int*)(xr + gg * 1024);
    }
    __builtin_amdgcn_sched_barrier(0);

    const char* gsrc = (const char*)hbs + ((size_t)p * 4 + g) * 32768;
    floatx4 acc0 = (floatx4){0.f,0.f,0.f,0.f};
    floatx4 acc1 = (floatx4){0.f,0.f,0.f,0.f};

    auto wait_chunk = [&](int c){
      if (s == 0) return;
      const int* fp2 = &flags[fb + c * 8 + (lane & 7)];
      while (true){
        int v = __hip_atomic_load(fp2, __ATOMIC_RELAXED, __HIP_MEMORY_SCOPE_AGENT);
        if (__all(v >= s)) break;
        __builtin_amdgcn_s_sleep(1);
        if (--bail < 0) break;
      }
    };

    unsigned long long loA[8], hiA[8], loB[8], hiB[8];
    auto issue8 = [&](unsigned long long (&lo)[8], unsigned long long (&hi)[8], int ch){
      #pragma unroll
      for (int i = 0; i < 8; i++){
        const unsigned long long* sp2 = (const unsigned long long*)(gsrc + (ch * 8 + i) * 1024 + lane * 16);
        lo[i] = __hip_atomic_load(sp2,     __ATOMIC_RELAXED, __HIP_MEMORY_SCOPE_AGENT);
        hi[i] = __hip_atomic_load(sp2 + 1, __ATOMIC_RELAXED, __HIP_MEMORY_SCOPE_AGENT);
      }
    };
    auto crunch8 = [&](unsigned long long (&lo)[8], unsigned long long (&hi)[8], int ch){
      #pragma unroll
      for (int i = 0; i < 8; i++){
        union { unsigned long long q[2]; short8 v; } u;
        u.q[0] = lo[i]; u.q[1] = hi[i];
        asm volatile("s_nop 1\n\tv_mfma_f32_16x16x32_bf16 %0, %1, %2, %0"
                     : "+v"(acc0) : "v"(u.v), "a"(bfrag0[ch * 8 + i]));
        asm volatile("v_mfma_f32_16x16x32_bf16 %0, %1, %2, %0"
                     : "+v"(acc1) : "v"(u.v), "a"(bfrag1[ch * 8 + i]));
      }
    };
    wait_chunk(0);
    issue8(loA, hiA, 0);
    wait_chunk(1);
    issue8(loB, hiB, 1);
    crunch8(loA, hiA, 0);
    wait_chunk(2);
    issue8(loA, hiA, 2);
    crunch8(loB, hiB, 1);
    wait_chunk(3);
    issue8(loB, hiB, 3);
    crunch8(loA, hiA, 2);
    crunch8(loB, hiB, 3);
    asm volatile("s_nop 7\n\ts_nop 7\n\ts_nop 7" ::: "memory");

    {
      const int r0 = (lane >> 4) * 4;
      const int cl = lane & 15;
      #pragma unroll
      for (int r = 0; r < 4; r++){
        sm.glds[w][r0 + r][cl]      = acc0[r];
        sm.glds[w][r0 + r][16 + cl] = acc1[r];
      }
    }
    __syncthreads();                                    // B3

    float hout[2];
    #pragma unroll
    for (int d = 0; d < 2; d++){
      float fv = fsigmoid(sm.glds[0][b][cc2 + d] + bf2f((unsigned short)(xu[0] >> (16 * d))));
      float iv = fsigmoid(sm.glds[1][b][cc2 + d] + bf2f((unsigned short)(xu[1] >> (16 * d))));
      float ov = fsigmoid(sm.glds[2][b][cc2 + d] + bf2f((unsigned short)(xu[2] >> (16 * d))));
      float gv = fsigmoid(sm.glds[3][b][cc2 + d] + bf2f((unsigned short)(xu[3] >> (16 * d))));  // sigmoid
      float cv = fv * cst[d] + iv * gv;
      cst[d] = cv;
      hout[d] = ov * ftanh(cv);
    }

    {
      unsigned int hv = (unsigned int)f2bf(hout[0]) | ((unsigned int)f2bf(hout[1]) << 16);
      unsigned int* dst = (unsigned int*)((char*)hbs + ((size_t)(p ^ 1) * 4 + g) * 32768 + j * 1024
                + (((cc2 >> 3) * 16 + b) << 4) + ((cc2 & 7) << 1));
      __hip_atomic_store(dst, hv, __ATOMIC_RELAXED, __HIP_MEMORY_SCOPE_AGENT);
    }

    if (s == 1023){
      *(floatx2*)&hlast[(size_t)(B0 + b) * 1024 + gc0 + cc2] = (floatx2){hout[0], hout[1]};
      *(floatx2*)&clast[(size_t)(B0 + b) * 1024 + gc0 + cc2] = cst;
    }

    asm volatile("s_waitcnt vmcnt(0)" ::: "memory");
    __syncthreads();                                    // B4
    if (t == 0)
      __hip_atomic_store(&flags[fb + j], s + 1, __ATOMIC_RELAXED, __HIP_MEMORY_SCOPE_AGENT);

    *(floatx2*)&out[((size_t)(B0 + b) * 1024 + s) * 1024 + gc0 + cc2] = (floatx2){hout[0], hout[1]};
  }

  *(floatx2*)&cstate[(size_t)(B0 + b) * 1024 + gc0 + cc2] = cst;
}

extern "C" void kernel_launch(void* const* d_in, const int* in_sizes, int n_in,
                              void* d_out, int out_size, void* d_ws, size_t ws_size,
                              hipStream_t stream)
{
  (void)in_sizes; (void)n_in; (void)out_size;
  const float* input_emb = (const float*)d_in[0];
  const float* W   = (const float*)d_in[1];
  const float* bWp = (const float*)d_in[2];
  const float* U   = (const float*)d_in[3];
  const float* bUp = (const float*)d_in[4];
  float* out   = (float*)d_out;
  float* hlast = out + (size_t)64 * 1024 * 1024;
  float* clast = hlast + 64 * 1024;

  char* base = (char*)d_ws;
  unsigned short* Wt  = (unsigned short*)base;  base += 8388608;   // [4096][1024] bf16
  unsigned short* Ut  = (unsigned short*)base;  base += 8388608;   // [4096][1024] bf16
  unsigned short* hbs = (unsigned short*)base;  base += 262144;    // [2][4][32KB] group h
  float* cstate       = (float*)base;           base += 262144;    // [64][1024] f32
  int* flags          = (int*)base;             base += 8192;      // [4][32] ints (+pad)
  int* mcnt           = (int*)base;             base += 4096;      // [SC/2] m-tile counters
  size_t fixed = (size_t)(base - (char*)d_ws);
  size_t avail = ws_size > fixed ? ws_size - fixed : 0;
  int SC = 1024;
  while (SC > 8 && (size_t)SC * 655360ull > avail) SC >>= 1;
  unsigned short* Abuf = (unsigned short*)base; base += (size_t)SC * 131072;  // [SC*64][1024] bf16
  unsigned short* xpb  = (unsigned short*)base;                               // [SC*64][4096] bf16

  hipMemsetAsync(flags, 0, 8192, stream);
  hipMemsetAsync(hbs, 0, 262144, stream);       // h0 = 0 (both parities)

  k_transpose_bf16<<<dim3(16, 16, 4), 256, 0, stream>>>(W, Wt);
  k_transpose_bf16<<<dim3(16, 16, 4), 256, 0, stream>>>(U, Ut);

  int nch = 1024 / SC;
  for (int cc = 0; cc < nch; cc++){
    int s0 = cc * SC;
    hipMemsetAsync(mcnt, 0, 4096, stream);
    k_convert_x<<<SC * 64, 256, 0, stream>>>(input_emb, Abuf, s0);
    k_fused<<<256, 256, 0, stream>>>(Abuf, Wt, bWp, bUp, xpb, Ut, hbs, cstate,
                                     out, hlast, clast, flags, mcnt, s0, SC);
  }
}